// Round 1
// baseline (2997.828 us; speedup 1.0000x reference)
//
#include <hip/hip_runtime.h>
#include <math.h>

// Swin block: B=128, H=W=56, C=96, WS=7, SHIFT=3, NH=3, d=32, L=49, FF=4
// Kernel A: fused shift + window partition + LN1 + QKV + masked softmax attn
//           + output proj + residual  -> writes res into d_out
// Kernel B: fused LN2 + MLP (gelu exact) + residual, in-place on d_out

#define NT_A 512
#define NT_B 256
#define TOK  32

__global__ __launch_bounds__(NT_A, 2)
void swin_attn_kernel(const float* __restrict__ x,
                      const float* __restrict__ ln1g, const float* __restrict__ ln1b,
                      const float* __restrict__ wq, const float* __restrict__ wk,
                      const float* __restrict__ wv, const float* __restrict__ wo,
                      const float* __restrict__ bo,
                      float* __restrict__ res)
{
    // padded rows: 52 (so 4-token tiles never index OOB), stride 97 (bank spread)
    __shared__ float hb[52][97];   // raw window -> LN'd h -> (reused) attn output o
    __shared__ float qb[52][97];
    __shared__ float kb[52][97];
    __shared__ float vb[52][97];
    __shared__ float sc[3][49][49];
    __shared__ float mu[49], rstd[49];
    __shared__ int   rid[49];

    const int tid = threadIdx.x;
    const int wid = blockIdx.x;
    const int b  = wid >> 6;
    const int w  = wid & 63;
    const int wi = w >> 3, wj = w & 7;

    // ---- load shifted window (gather) ----
    for (int idx = tid; idx < 49 * 96; idx += NT_A) {
        int t = idx / 96, c = idx - t * 96;
        int i = wi * 7 + t / 7;
        int j = wj * 7 + t % 7;
        int si = i + 3; if (si >= 56) si -= 56;   // roll(x, -3): shifted[i]=x[(i+3)%56]
        int sj = j + 3; if (sj >= 56) sj -= 56;
        hb[t][c] = x[((b * 56 + si) * 56 + sj) * 96 + c];
    }
    if (tid < 49) {
        int t = tid;
        int i = wi * 7 + t / 7;
        int j = wj * 7 + t % 7;
        int ri = (i <= 48) ? 0 : (i <= 52 ? 1 : 2);
        int ci = (j <= 48) ? 0 : (j <= 52 ? 1 : 2);
        rid[t] = ri * 3 + ci;
    }
    __syncthreads();

    // ---- LN1 stats: 8 lanes per token ----
    {
        int t = tid >> 3, l = tid & 7;
        if (t < 49) {
            float s = 0.f, s2 = 0.f;
            for (int c = l; c < 96; c += 8) { float v = hb[t][c]; s += v; s2 += v * v; }
            for (int m = 1; m < 8; m <<= 1) { s += __shfl_xor(s, m); s2 += __shfl_xor(s2, m); }
            if (l == 0) {
                float mean = s * (1.f / 96.f);
                mu[t]   = mean;
                rstd[t] = rsqrtf(s2 * (1.f / 96.f) - mean * mean + 1e-5f);
            }
        }
    }
    __syncthreads();
    for (int idx = tid; idx < 49 * 96; idx += NT_A) {
        int t = idx / 96, c = idx - t * 96;
        hb[t][c] = (hb[t][c] - mu[t]) * rstd[t] * ln1g[c] + ln1b[c];
    }
    __syncthreads();

    // ---- QKV: 3 matrices x (13 token-tiles x 24 ch-tiles), 4x4 register tiles ----
    for (int idx = tid; idx < 3 * 13 * 24; idx += NT_A) {
        int m  = idx / 312;
        int r  = idx - m * 312;
        int tt = r / 24;
        int cc = (r - tt * 24) * 4;
        const float* wm = (m == 0) ? wq : (m == 1) ? wk : wv;
        float* ob = (m == 0) ? &qb[0][0] : (m == 1) ? &kb[0][0] : &vb[0][0];
        int t0 = tt * 4;
        const float* h0 = &hb[t0][0];
        const float* h1 = &hb[t0 + 1][0];
        const float* h2 = &hb[t0 + 2][0];
        const float* h3 = &hb[t0 + 3][0];
        float a00=0.f,a01=0.f,a02=0.f,a03=0.f;
        float a10=0.f,a11=0.f,a12=0.f,a13=0.f;
        float a20=0.f,a21=0.f,a22=0.f,a23=0.f;
        float a30=0.f,a31=0.f,a32=0.f,a33=0.f;
        #pragma unroll 4
        for (int k = 0; k < 96; k++) {
            float4 wr = *(const float4*)(wm + k * 96 + cc);
            float e0 = h0[k], e1 = h1[k], e2 = h2[k], e3 = h3[k];
            a00 += e0 * wr.x; a01 += e0 * wr.y; a02 += e0 * wr.z; a03 += e0 * wr.w;
            a10 += e1 * wr.x; a11 += e1 * wr.y; a12 += e1 * wr.z; a13 += e1 * wr.w;
            a20 += e2 * wr.x; a21 += e2 * wr.y; a22 += e2 * wr.z; a23 += e2 * wr.w;
            a30 += e3 * wr.x; a31 += e3 * wr.y; a32 += e3 * wr.z; a33 += e3 * wr.w;
        }
        float accs[4][4] = {{a00,a01,a02,a03},{a10,a11,a12,a13},{a20,a21,a22,a23},{a30,a31,a32,a33}};
        #pragma unroll
        for (int ii = 0; ii < 4; ii++) {
            int t = t0 + ii;
            if (t < 49) {
                float* orow = ob + t * 97 + cc;
                orow[0] = accs[ii][0]; orow[1] = accs[ii][1];
                orow[2] = accs[ii][2]; orow[3] = accs[ii][3];
            }
        }
    }
    __syncthreads();

    // ---- scores: s[h][q][k] = (q . k)/sqrt(32) + mask ----
    for (int idx = tid; idx < 3 * 49 * 13; idx += NT_A) {
        int hh = idx / 637;
        int r  = idx - hh * 637;
        int qi = r / 13;
        int k0 = (r - qi * 13) * 4;
        const float* qrow = &qb[qi][hh * 32];
        const float* k0r = &kb[k0][hh * 32];
        const float* k1r = &kb[k0 + 1][hh * 32];
        const float* k2r = &kb[k0 + 2][hh * 32];
        const float* k3r = &kb[k0 + 3][hh * 32];
        float a0 = 0.f, a1 = 0.f, a2 = 0.f, a3 = 0.f;
        #pragma unroll 4
        for (int dd = 0; dd < 32; dd++) {
            float qv = qrow[dd];
            a0 += qv * k0r[dd];
            a1 += qv * k1r[dd];
            a2 += qv * k2r[dd];
            a3 += qv * k3r[dd];
        }
        float accs[4] = {a0, a1, a2, a3};
        int rq = rid[qi];
        #pragma unroll
        for (int jj = 0; jj < 4; jj++) {
            int ki = k0 + jj;
            if (ki < 49) {
                float sv = accs[jj] * 0.1767766952966369f;  // 1/sqrt(32)
                if (rid[ki] != rq) sv = -INFINITY;
                sc[hh][qi][ki] = sv;
            }
        }
    }
    __syncthreads();

    // ---- softmax over rows (hh,qi): 8-lane groups ----
    {
        int grp = tid >> 3, l = tid & 7;
        for (int row = grp; row < 147; row += NT_A / 8) {
            float* srow = &sc[0][0][0] + row * 49;
            float m = -INFINITY;
            for (int ki = l; ki < 49; ki += 8) m = fmaxf(m, srow[ki]);
            for (int msk = 1; msk < 8; msk <<= 1) m = fmaxf(m, __shfl_xor(m, msk));
            float ssum = 0.f;
            for (int ki = l; ki < 49; ki += 8) {
                float e = expf(srow[ki] - m);
                srow[ki] = e;
                ssum += e;
            }
            for (int msk = 1; msk < 8; msk <<= 1) ssum += __shfl_xor(ssum, msk);
            float inv = 1.f / ssum;
            for (int ki = l; ki < 49; ki += 8) srow[ki] *= inv;
        }
    }
    __syncthreads();

    // ---- PV: o[q][c] = sum_k p[h][q][k] * v[k][c]   (o reuses hb) ----
    for (int idx = tid; idx < 49 * 24; idx += NT_A) {
        int qi = idx / 24;
        int c0 = (idx - qi * 24) * 4;
        int hh = c0 >> 5;
        const float* prow = &sc[hh][qi][0];
        float a0 = 0.f, a1 = 0.f, a2 = 0.f, a3 = 0.f;
        #pragma unroll 7
        for (int ki = 0; ki < 49; ki++) {
            float p = prow[ki];
            const float* vr = &vb[ki][c0];
            a0 += p * vr[0];
            a1 += p * vr[1];
            a2 += p * vr[2];
            a3 += p * vr[3];
        }
        float* orow = &hb[qi][c0];
        orow[0] = a0; orow[1] = a1; orow[2] = a2; orow[3] = a3;
    }
    __syncthreads();

    // ---- out proj + bias + residual; write to res at unshifted coords ----
    for (int idx = tid; idx < 13 * 24; idx += NT_A) {
        int tt = idx / 24;
        int cc = (idx - tt * 24) * 4;
        int t0 = tt * 4;
        const float* o0 = &hb[t0][0];
        const float* o1 = &hb[t0 + 1][0];
        const float* o2 = &hb[t0 + 2][0];
        const float* o3 = &hb[t0 + 3][0];
        float a00=0.f,a01=0.f,a02=0.f,a03=0.f;
        float a10=0.f,a11=0.f,a12=0.f,a13=0.f;
        float a20=0.f,a21=0.f,a22=0.f,a23=0.f;
        float a30=0.f,a31=0.f,a32=0.f,a33=0.f;
        #pragma unroll 4
        for (int k = 0; k < 96; k++) {
            float4 wr = *(const float4*)(wo + k * 96 + cc);
            float e0 = o0[k], e1 = o1[k], e2 = o2[k], e3 = o3[k];
            a00 += e0 * wr.x; a01 += e0 * wr.y; a02 += e0 * wr.z; a03 += e0 * wr.w;
            a10 += e1 * wr.x; a11 += e1 * wr.y; a12 += e1 * wr.z; a13 += e1 * wr.w;
            a20 += e2 * wr.x; a21 += e2 * wr.y; a22 += e2 * wr.z; a23 += e2 * wr.w;
            a30 += e3 * wr.x; a31 += e3 * wr.y; a32 += e3 * wr.z; a33 += e3 * wr.w;
        }
        float accs[4][4] = {{a00,a01,a02,a03},{a10,a11,a12,a13},{a20,a21,a22,a23},{a30,a31,a32,a33}};
        float4 bo4 = *(const float4*)(bo + cc);
        #pragma unroll
        for (int ii = 0; ii < 4; ii++) {
            int t = t0 + ii;
            if (t < 49) {
                int i = wi * 7 + t / 7;
                int j = wj * 7 + t % 7;
                int si = i + 3; if (si >= 56) si -= 56;
                int sj = j + 3; if (sj >= 56) sj -= 56;
                int gbase = ((b * 56 + si) * 56 + sj) * 96 + cc;
                float4 xv = *(const float4*)(x + gbase);
                float4 ov;
                ov.x = accs[ii][0] + bo4.x + xv.x;
                ov.y = accs[ii][1] + bo4.y + xv.y;
                ov.z = accs[ii][2] + bo4.z + xv.z;
                ov.w = accs[ii][3] + bo4.w + xv.w;
                *(float4*)(res + gbase) = ov;
            }
        }
    }
}

__global__ __launch_bounds__(NT_B, 2)
void swin_mlp_kernel(const float* resin,       // aliases out (in-place, owner-exclusive)
                     const float* __restrict__ ln2g, const float* __restrict__ ln2b,
                     const float* __restrict__ w1, const float* __restrict__ b1,
                     const float* __restrict__ w2, const float* __restrict__ b2,
                     float* out)
{
    __shared__ float tin[TOK][97];     // raw -> LN'd
    __shared__ float hid[TOK][385];    // gelu(h2 @ w1 + b1)
    __shared__ float mu[TOK], rstd[TOK];

    const int tid  = threadIdx.x;
    const int tok0 = blockIdx.x * TOK;

    // load
    for (int idx = tid; idx < TOK * 96; idx += NT_B) {
        int t = idx / 96, c = idx - t * 96;
        tin[t][c] = resin[(tok0 + t) * 96 + c];
    }
    __syncthreads();

    // LN2 stats: exactly 32 groups of 8 lanes
    {
        int t = tid >> 3, l = tid & 7;
        float s = 0.f, s2 = 0.f;
        for (int c = l; c < 96; c += 8) { float v = tin[t][c]; s += v; s2 += v * v; }
        for (int m = 1; m < 8; m <<= 1) { s += __shfl_xor(s, m); s2 += __shfl_xor(s2, m); }
        if (l == 0) {
            float mean = s * (1.f / 96.f);
            mu[t]   = mean;
            rstd[t] = rsqrtf(s2 * (1.f / 96.f) - mean * mean + 1e-5f);
        }
    }
    __syncthreads();
    for (int idx = tid; idx < TOK * 96; idx += NT_B) {
        int t = idx / 96, c = idx - t * 96;
        tin[t][c] = (tin[t][c] - mu[t]) * rstd[t] * ln2g[c] + ln2b[c];
    }
    __syncthreads();

    // hidden = gelu(tin @ w1 + b1):  8 token-tiles x 96 ch-tiles (4x4)
    for (int idx = tid; idx < 8 * 96; idx += NT_B) {
        int tt = idx / 96;
        int cc = (idx - tt * 96) * 4;
        int t0 = tt * 4;
        const float* h0 = &tin[t0][0];
        const float* h1 = &tin[t0 + 1][0];
        const float* h2 = &tin[t0 + 2][0];
        const float* h3 = &tin[t0 + 3][0];
        float a00=0.f,a01=0.f,a02=0.f,a03=0.f;
        float a10=0.f,a11=0.f,a12=0.f,a13=0.f;
        float a20=0.f,a21=0.f,a22=0.f,a23=0.f;
        float a30=0.f,a31=0.f,a32=0.f,a33=0.f;
        #pragma unroll 4
        for (int k = 0; k < 96; k++) {
            float4 wr = *(const float4*)(w1 + k * 384 + cc);
            float e0 = h0[k], e1 = h1[k], e2 = h2[k], e3 = h3[k];
            a00 += e0 * wr.x; a01 += e0 * wr.y; a02 += e0 * wr.z; a03 += e0 * wr.w;
            a10 += e1 * wr.x; a11 += e1 * wr.y; a12 += e1 * wr.z; a13 += e1 * wr.w;
            a20 += e2 * wr.x; a21 += e2 * wr.y; a22 += e2 * wr.z; a23 += e2 * wr.w;
            a30 += e3 * wr.x; a31 += e3 * wr.y; a32 += e3 * wr.z; a33 += e3 * wr.w;
        }
        float accs[4][4] = {{a00,a01,a02,a03},{a10,a11,a12,a13},{a20,a21,a22,a23},{a30,a31,a32,a33}};
        #pragma unroll
        for (int ii = 0; ii < 4; ii++) {
            #pragma unroll
            for (int jj = 0; jj < 4; jj++) {
                float v = accs[ii][jj] + b1[cc + jj];
                v = 0.5f * v * (1.f + erff(v * 0.70710678118654752f));  // exact gelu
                hid[t0 + ii][cc + jj] = v;
            }
        }
    }
    __syncthreads();

    // out = hid @ w2 + b2 + t:  8 token-tiles x 32 ch-tiles (4x3) = 256 == NT_B
    {
        int tt = tid >> 5;
        int c0 = (tid & 31) * 3;
        int t0 = tt * 4;
        const float* g0 = &hid[t0][0];
        const float* g1 = &hid[t0 + 1][0];
        const float* g2 = &hid[t0 + 2][0];
        const float* g3 = &hid[t0 + 3][0];
        float a00=0.f,a01=0.f,a02=0.f;
        float a10=0.f,a11=0.f,a12=0.f;
        float a20=0.f,a21=0.f,a22=0.f;
        float a30=0.f,a31=0.f,a32=0.f;
        #pragma unroll 4
        for (int k = 0; k < 384; k++) {
            const float* wr = w2 + k * 96 + c0;
            float wx = wr[0], wy = wr[1], wz = wr[2];
            float e0 = g0[k], e1 = g1[k], e2 = g2[k], e3 = g3[k];
            a00 += e0 * wx; a01 += e0 * wy; a02 += e0 * wz;
            a10 += e1 * wx; a11 += e1 * wy; a12 += e1 * wz;
            a20 += e2 * wx; a21 += e2 * wy; a22 += e2 * wz;
            a30 += e3 * wx; a31 += e3 * wy; a32 += e3 * wz;
        }
        float accs[4][3] = {{a00,a01,a02},{a10,a11,a12},{a20,a21,a22},{a30,a31,a32}};
        #pragma unroll
        for (int ii = 0; ii < 4; ii++) {
            #pragma unroll
            for (int jj = 0; jj < 3; jj++) {
                int c = c0 + jj;
                int gi = (tok0 + t0 + ii) * 96 + c;
                out[gi] = resin[gi] + accs[ii][jj] + b2[c];
            }
        }
    }
}

extern "C" void kernel_launch(void* const* d_in, const int* in_sizes, int n_in,
                              void* d_out, int out_size, void* d_ws, size_t ws_size,
                              hipStream_t stream)
{
    const float* x    = (const float*)d_in[0];
    const float* ln1g = (const float*)d_in[1];
    const float* ln1b = (const float*)d_in[2];
    const float* wq   = (const float*)d_in[3];
    const float* wk   = (const float*)d_in[4];
    const float* wv   = (const float*)d_in[5];
    const float* wo   = (const float*)d_in[6];
    const float* bo   = (const float*)d_in[7];
    const float* w1   = (const float*)d_in[8];
    const float* b1   = (const float*)d_in[9];
    const float* w2   = (const float*)d_in[10];
    const float* b2   = (const float*)d_in[11];
    const float* ln2g = (const float*)d_in[12];
    const float* ln2b = (const float*)d_in[13];
    float* out = (float*)d_out;

    // 128 images * 64 windows = 8192 window-blocks
    swin_attn_kernel<<<8192, NT_A, 0, stream>>>(x, ln1g, ln1b, wq, wk, wv, wo, bo, out);
    // 401408 tokens / 32 per block = 12544 blocks; in-place LN2+MLP+residual
    swin_mlp_kernel<<<12544, NT_B, 0, stream>>>(out, ln2g, ln2b, w1, b1, w2, b2, out);
}

// Round 4
// 1644.532 us; speedup vs baseline: 1.8229x; 1.8229x over previous
//
#include <hip/hip_runtime.h>
#include <math.h>

// Swin block: B=128, H=W=56, C=96, WS=7, SHIFT=3, NH=3, d=32, L=49, FF=4
// Kernel A (fp32, 1024 thr): shift + window + LN1 + QKV + masked softmax attn
//                            + out-proj + residual -> d_out
// Kernel B (bf16 MFMA, 512 thr): LN2 + MLP (exact gelu) + residual, in-place.

#define NT_A 1024
#define NT_B 512
#define TOKB 64

using short8 = __attribute__((ext_vector_type(8))) short;
using f32x4  = __attribute__((ext_vector_type(4))) float;

__device__ __forceinline__ ushort f2bf(float x) {
    unsigned u = __float_as_uint(x);
    unsigned r = (u + 0x7fffu + ((u >> 16) & 1u)) >> 16;
    return (ushort)r;
}

// ---------------------------------------------------------------- kernel A
__global__ __launch_bounds__(NT_A, 4)
void swin_attn_kernel(const float* __restrict__ x,
                      const float* __restrict__ ln1g, const float* __restrict__ ln1b,
                      const float* __restrict__ wq, const float* __restrict__ wk,
                      const float* __restrict__ wv, const float* __restrict__ wo,
                      const float* __restrict__ bo,
                      float* __restrict__ res)
{
    // stride 100 floats = 400B: 16B-aligned rows (float4-able), 25-bank row skew
    __shared__ float hb[52][100];   // raw window -> LN'd h -> attn output o
    __shared__ float qb[52][100];
    __shared__ float kb[52][100];
    __shared__ float vb[52][100];
    __shared__ float sc[3][49][49];
    __shared__ float mu[49], rstd[49];
    __shared__ int   rid[49];

    const int tid = threadIdx.x;
    const int wid = blockIdx.x;
    const int b  = wid >> 6;
    const int w  = wid & 63;
    const int wi = w >> 3, wj = w & 7;

    // ---- load shifted window (float4 gather) ----
    for (int idx = tid; idx < 49 * 24; idx += NT_A) {
        int t = idx / 24, c4 = (idx - t * 24) * 4;
        int i = wi * 7 + t / 7;
        int j = wj * 7 + t % 7;
        int si = i + 3; if (si >= 56) si -= 56;   // roll(x,-3)
        int sj = j + 3; if (sj >= 56) sj -= 56;
        float4 v = *(const float4*)(x + ((b * 56 + si) * 56 + sj) * 96 + c4);
        *(float4*)&hb[t][c4] = v;
    }
    if (tid < 49) {
        int t = tid;
        int i = wi * 7 + t / 7;
        int j = wj * 7 + t % 7;
        int ri = (i <= 48) ? 0 : (i <= 52 ? 1 : 2);
        int ci = (j <= 48) ? 0 : (j <= 52 ? 1 : 2);
        rid[t] = ri * 3 + ci;
    }
    __syncthreads();

    // ---- LN1 stats: 8 lanes per token ----
    {
        int t = tid >> 3, l = tid & 7;
        if (t < 49) {
            float s = 0.f, s2 = 0.f;
            for (int c = l; c < 96; c += 8) { float v = hb[t][c]; s += v; s2 += v * v; }
            for (int m = 1; m < 8; m <<= 1) { s += __shfl_xor(s, m); s2 += __shfl_xor(s2, m); }
            if (l == 0) {
                float mean = s * (1.f / 96.f);
                mu[t]   = mean;
                rstd[t] = rsqrtf(s2 * (1.f / 96.f) - mean * mean + 1e-5f);
            }
        }
    }
    __syncthreads();
    for (int idx = tid; idx < 49 * 96; idx += NT_A) {
        int t = idx / 96, c = idx - t * 96;
        hb[t][c] = (hb[t][c] - mu[t]) * rstd[t] * ln1g[c] + ln1b[c];
    }
    __syncthreads();

    // ---- QKV: 3 x (13 token-tiles x 24 ch-tiles), 4x4 register tiles ----
    for (int idx = tid; idx < 3 * 13 * 24; idx += NT_A) {
        int m  = idx / 312;
        int r  = idx - m * 312;
        int tt = r / 24;
        int cc = (r - tt * 24) * 4;
        const float* wm = (m == 0) ? wq : (m == 1) ? wk : wv;
        float* ob = (m == 0) ? &qb[0][0] : (m == 1) ? &kb[0][0] : &vb[0][0];
        int t0 = tt * 4;
        const float* h0 = &hb[t0][0];
        const float* h1 = &hb[t0 + 1][0];
        const float* h2 = &hb[t0 + 2][0];
        const float* h3 = &hb[t0 + 3][0];
        float a00=0.f,a01=0.f,a02=0.f,a03=0.f;
        float a10=0.f,a11=0.f,a12=0.f,a13=0.f;
        float a20=0.f,a21=0.f,a22=0.f,a23=0.f;
        float a30=0.f,a31=0.f,a32=0.f,a33=0.f;
        #pragma unroll 4
        for (int k = 0; k < 96; k++) {
            float4 wr = *(const float4*)(wm + k * 96 + cc);
            float e0 = h0[k], e1 = h1[k], e2 = h2[k], e3 = h3[k];
            a00 += e0 * wr.x; a01 += e0 * wr.y; a02 += e0 * wr.z; a03 += e0 * wr.w;
            a10 += e1 * wr.x; a11 += e1 * wr.y; a12 += e1 * wr.z; a13 += e1 * wr.w;
            a20 += e2 * wr.x; a21 += e2 * wr.y; a22 += e2 * wr.z; a23 += e2 * wr.w;
            a30 += e3 * wr.x; a31 += e3 * wr.y; a32 += e3 * wr.z; a33 += e3 * wr.w;
        }
        float accs[4][4] = {{a00,a01,a02,a03},{a10,a11,a12,a13},{a20,a21,a22,a23},{a30,a31,a32,a33}};
        #pragma unroll
        for (int ii = 0; ii < 4; ii++) {
            int t = t0 + ii;
            if (t < 49) {
                float4 ov = make_float4(accs[ii][0], accs[ii][1], accs[ii][2], accs[ii][3]);
                *(float4*)(ob + t * 100 + cc) = ov;
            }
        }
    }
    __syncthreads();

    // ---- scores: s[h][q][k] = (q.k)/sqrt(32) + mask ----
    for (int idx = tid; idx < 3 * 49 * 13; idx += NT_A) {
        int hh = idx / 637;
        int r  = idx - hh * 637;
        int qi = r / 13;
        int k0 = (r - qi * 13) * 4;
        const float* qrow = &qb[qi][hh * 32];
        const float* k0r = &kb[k0][hh * 32];
        const float* k1r = &kb[k0 + 1][hh * 32];
        const float* k2r = &kb[k0 + 2][hh * 32];
        const float* k3r = &kb[k0 + 3][hh * 32];
        float a0 = 0.f, a1 = 0.f, a2 = 0.f, a3 = 0.f;
        #pragma unroll 4
        for (int dd = 0; dd < 32; dd++) {
            float qv = qrow[dd];
            a0 += qv * k0r[dd];
            a1 += qv * k1r[dd];
            a2 += qv * k2r[dd];
            a3 += qv * k3r[dd];
        }
        float accs[4] = {a0, a1, a2, a3};
        int rq = rid[qi];
        #pragma unroll
        for (int jj = 0; jj < 4; jj++) {
            int ki = k0 + jj;
            if (ki < 49) {
                float sv = accs[jj] * 0.1767766952966369f;  // 1/sqrt(32)
                if (rid[ki] != rq) sv = -INFINITY;
                sc[hh][qi][ki] = sv;
            }
        }
    }
    __syncthreads();

    // ---- softmax over 147 rows: 8-lane groups ----
    {
        int grp = tid >> 3, l = tid & 7;
        for (int row = grp; row < 147; row += NT_A / 8) {
            float* srow = &sc[0][0][0] + row * 49;
            float m = -INFINITY;
            for (int ki = l; ki < 49; ki += 8) m = fmaxf(m, srow[ki]);
            for (int msk = 1; msk < 8; msk <<= 1) m = fmaxf(m, __shfl_xor(m, msk));
            float ssum = 0.f;
            for (int ki = l; ki < 49; ki += 8) {
                float e = expf(srow[ki] - m);
                srow[ki] = e;
                ssum += e;
            }
            for (int msk = 1; msk < 8; msk <<= 1) ssum += __shfl_xor(ssum, msk);
            float inv = 1.f / ssum;
            for (int ki = l; ki < 49; ki += 8) srow[ki] *= inv;
        }
    }
    __syncthreads();

    // ---- PV: o[q][c] = sum_k p[h][q][k] * v[k][c]  (o reuses hb) ----
    for (int idx = tid; idx < 49 * 24; idx += NT_A) {
        int qi = idx / 24;
        int c0 = (idx - qi * 24) * 4;
        int hh = c0 >> 5;
        const float* prow = &sc[hh][qi][0];
        float a0 = 0.f, a1 = 0.f, a2 = 0.f, a3 = 0.f;
        #pragma unroll 7
        for (int ki = 0; ki < 49; ki++) {
            float p = prow[ki];
            float4 vv = *(const float4*)&vb[ki][c0];
            a0 += p * vv.x;
            a1 += p * vv.y;
            a2 += p * vv.z;
            a3 += p * vv.w;
        }
        *(float4*)&hb[qi][c0] = make_float4(a0, a1, a2, a3);
    }
    __syncthreads();

    // ---- out proj + bias + residual at unshifted coords ----
    for (int idx = tid; idx < 13 * 24; idx += NT_A) {
        int tt = idx / 24;
        int cc = (idx - tt * 24) * 4;
        int t0 = tt * 4;
        const float* o0 = &hb[t0][0];
        const float* o1 = &hb[t0 + 1][0];
        const float* o2 = &hb[t0 + 2][0];
        const float* o3 = &hb[t0 + 3][0];
        float a00=0.f,a01=0.f,a02=0.f,a03=0.f;
        float a10=0.f,a11=0.f,a12=0.f,a13=0.f;
        float a20=0.f,a21=0.f,a22=0.f,a23=0.f;
        float a30=0.f,a31=0.f,a32=0.f,a33=0.f;
        #pragma unroll 4
        for (int k = 0; k < 96; k++) {
            float4 wr = *(const float4*)(wo + k * 96 + cc);
            float e0 = o0[k], e1 = o1[k], e2 = o2[k], e3 = o3[k];
            a00 += e0 * wr.x; a01 += e0 * wr.y; a02 += e0 * wr.z; a03 += e0 * wr.w;
            a10 += e1 * wr.x; a11 += e1 * wr.y; a12 += e1 * wr.z; a13 += e1 * wr.w;
            a20 += e2 * wr.x; a21 += e2 * wr.y; a22 += e2 * wr.z; a23 += e2 * wr.w;
            a30 += e3 * wr.x; a31 += e3 * wr.y; a32 += e3 * wr.z; a33 += e3 * wr.w;
        }
        float accs[4][4] = {{a00,a01,a02,a03},{a10,a11,a12,a13},{a20,a21,a22,a23},{a30,a31,a32,a33}};
        float4 bo4 = *(const float4*)(bo + cc);
        #pragma unroll
        for (int ii = 0; ii < 4; ii++) {
            int t = t0 + ii;
            if (t < 49) {
                int i = wi * 7 + t / 7;
                int j = wj * 7 + t % 7;
                int si = i + 3; if (si >= 56) si -= 56;
                int sj = j + 3; if (sj >= 56) sj -= 56;
                int gbase = ((b * 56 + si) * 56 + sj) * 96 + cc;
                float4 xv = *(const float4*)(x + gbase);
                float4 ov;
                ov.x = accs[ii][0] + bo4.x + xv.x;
                ov.y = accs[ii][1] + bo4.y + xv.y;
                ov.z = accs[ii][2] + bo4.z + xv.z;
                ov.w = accs[ii][3] + bo4.w + xv.w;
                *(float4*)(res + gbase) = ov;
            }
        }
    }
}

// ---------------------------------------------------------------- kernel B
// 64 tokens/block, 512 threads (8 waves). bf16 MFMA 16x16x32.
// Wave fragment layout (gfx950, guide-verified C/D):
//   A: row = lane&15, k = (lane>>4)*8 + i (8 contiguous bf16 -> ds_read_b128)
//   B: col = lane&15, k = (lane>>4)*8 + i
//   C/D: col = lane&15, row = (lane>>4)*4 + reg
__global__ __launch_bounds__(NT_B, 4)
void swin_mlp_mfma(const float* resin,     // aliases out (in-place, block-exclusive)
                   const float* __restrict__ ln2g, const float* __restrict__ ln2b,
                   const float* __restrict__ w1, const float* __restrict__ b1,
                   const float* __restrict__ w2, const float* __restrict__ b2,
                   float* out)
{
    __shared__ ushort aLds[64][104];   // LN'd tokens, bf16; 208B rows (16B-aligned)
    __shared__ ushort hLds[64][392];   // hidden (gelu out), bf16; 784B rows
    __shared__ ushort wS[96][40];      // w2 k-slice, transposed [n][k], 80B rows

    const int tid  = threadIdx.x;
    const int lane = tid & 63;
    const int wv   = tid >> 6;         // wave 0..7
    const int tok0 = blockIdx.x * TOKB;

    // ---- LN2 (8 lanes per token; 64 tokens exactly) -> aLds bf16 ----
    {
        int t = tid >> 3, l = tid & 7;
        const float* row = resin + (size_t)(tok0 + t) * 96;
        float v[12];
        float s = 0.f, s2 = 0.f;
        #pragma unroll
        for (int i = 0; i < 12; i++) {
            v[i] = row[l + 8 * i];
            s += v[i]; s2 += v[i] * v[i];
        }
        #pragma unroll
        for (int m = 1; m < 8; m <<= 1) { s += __shfl_xor(s, m); s2 += __shfl_xor(s2, m); }
        float mean = s * (1.f / 96.f);
        float rs = rsqrtf(s2 * (1.f / 96.f) - mean * mean + 1e-5f);
        #pragma unroll
        for (int i = 0; i < 12; i++) {
            int c = l + 8 * i;
            float hn = (v[i] - mean) * rs * ln2g[c] + ln2b[c];
            aLds[t][c] = f2bf(hn);
        }
    }
    __syncthreads();

    const int r = lane & 15;
    const int g = lane >> 4;

    // ---- GEMM1: [64x96] @ w1[96x384]; wave owns 48 cols (3 n-frags) ----
    {
        const int n0 = wv * 48;
        f32x4 acc[4][3] = {};
        #pragma unroll
        for (int kf = 0; kf < 3; kf++) {
            const int kk = kf * 32 + g * 8;
            short8 af[4];
            #pragma unroll
            for (int m = 0; m < 4; m++)
                af[m] = *(const short8*)&aLds[m * 16 + r][kk];
            short8 bv[3];
            #pragma unroll
            for (int nf = 0; nf < 3; nf++) {
                const float* wp = w1 + (size_t)kk * 384 + (n0 + nf * 16 + r);
                #pragma unroll
                for (int i = 0; i < 8; i++)
                    bv[nf][i] = (short)f2bf(wp[(size_t)i * 384]);
            }
            #pragma unroll
            for (int m = 0; m < 4; m++)
                #pragma unroll
                for (int nf = 0; nf < 3; nf++)
                    acc[m][nf] = __builtin_amdgcn_mfma_f32_16x16x32_bf16(
                        af[m], bv[nf], acc[m][nf], 0, 0, 0);
        }
        // bias + exact gelu -> hLds bf16
        #pragma unroll
        for (int nf = 0; nf < 3; nf++) {
            int col = n0 + nf * 16 + r;
            float bias = b1[col];
            #pragma unroll
            for (int m = 0; m < 4; m++) {
                #pragma unroll
                for (int q = 0; q < 4; q++) {
                    float val = acc[m][nf][q] + bias;
                    val = 0.5f * val * (1.f + erff(val * 0.70710678118654752f));
                    hLds[m * 16 + g * 4 + q][col] = f2bf(val);
                }
            }
        }
    }
    __syncthreads();

    // ---- GEMM2: [64x384] @ w2[384x96]; wave (m = wv&3, nh = wv>>2) ----
    {
        const int m  = wv & 3;
        const int n0 = (wv >> 2) * 48;
        f32x4 acc[3] = {};
        for (int kf = 0; kf < 12; kf++) {
            const int k0 = kf * 32;
            __syncthreads();   // previous slice fully consumed
            // stage w2[k0..k0+32][0..96] transposed+swizzled into wS
            for (int idx = tid; idx < 96 * 32; idx += NT_B) {
                int kk = idx / 96;
                int n  = idx - kk * 96;
                wS[n][kk ^ ((n & 3) << 3)] = f2bf(w2[(size_t)(k0 + kk) * 96 + n]);
            }
            __syncthreads();
            short8 af = *(const short8*)&hLds[m * 16 + r][k0 + g * 8];
            #pragma unroll
            for (int nf = 0; nf < 3; nf++) {
                int n = n0 + nf * 16 + r;
                short8 bf = *(const short8*)&wS[n][(g ^ (n & 3)) * 8];
                acc[nf] = __builtin_amdgcn_mfma_f32_16x16x32_bf16(af, bf, acc[nf], 0, 0, 0);
            }
        }
        // bias + residual -> out (in place; each gi touched by exactly one lane)
        #pragma unroll
        for (int nf = 0; nf < 3; nf++) {
            int col = n0 + nf * 16 + r;
            float bias = b2[col];
            #pragma unroll
            for (int q = 0; q < 4; q++) {
                int row = m * 16 + g * 4 + q;
                size_t gi = (size_t)(tok0 + row) * 96 + col;
                out[gi] = resin[gi] + acc[nf][q] + bias;
            }
        }
    }
}

extern "C" void kernel_launch(void* const* d_in, const int* in_sizes, int n_in,
                              void* d_out, int out_size, void* d_ws, size_t ws_size,
                              hipStream_t stream)
{
    const float* x    = (const float*)d_in[0];
    const float* ln1g = (const float*)d_in[1];
    const float* ln1b = (const float*)d_in[2];
    const float* wq   = (const float*)d_in[3];
    const float* wk   = (const float*)d_in[4];
    const float* wv   = (const float*)d_in[5];
    const float* wo   = (const float*)d_in[6];
    const float* bo   = (const float*)d_in[7];
    const float* w1   = (const float*)d_in[8];
    const float* b1   = (const float*)d_in[9];
    const float* w2   = (const float*)d_in[10];
    const float* b2   = (const float*)d_in[11];
    const float* ln2g = (const float*)d_in[12];
    const float* ln2b = (const float*)d_in[13];
    float* out = (float*)d_out;

    // 128 images * 64 windows = 8192 window-blocks
    swin_attn_kernel<<<8192, NT_A, 0, stream>>>(x, ln1g, ln1b, wq, wk, wv, wo, bo, out);
    // 401408 tokens / 64 = 6272 blocks; in-place LN2+MLP+residual
    swin_mlp_mfma<<<6272, NT_B, 0, stream>>>(out, ln2g, ln2b, w1, b1, w2, b2, out);
}